// Round 12
// baseline (293.219 us; speedup 1.0000x reference)
//
#include <hip/hip_runtime.h>
#include <hip/hip_bf16.h>

#define B_   4
#define S_   2048
#define D_   1024
#define H_   16
#define DH_  64
#define M_   (B_ * S_)

typedef __attribute__((ext_vector_type(8))) short  bfrag8;   // 8 bf16 = 4 VGPRs
typedef __attribute__((ext_vector_type(4))) float  facc4;    // 4 fp32 accum
typedef unsigned short u16;
typedef unsigned long long u64;

__device__ __forceinline__ u16 f2bf(float f) {
    union { __hip_bfloat16 h; u16 u; } c;
    c.h = __float2bfloat16(f);
    return c.u;
}

// manual RNE fp32->bf16 (finite inputs only)
__device__ __forceinline__ u16 bfr(float f) {
    unsigned b = __float_as_uint(f);
    return (u16)((b + 0x7FFFu + ((b >> 16) & 1u)) >> 16);
}

// async global->LDS, 16B per lane; LDS dest must be wave-uniform base + lane*16
__device__ __forceinline__ void gl_lds16(const u16* g, u16* l) {
    __builtin_amdgcn_global_load_lds((const __attribute__((address_space(1))) void*)g,
                                     (__attribute__((address_space(3))) void*)l,
                                     16, 0, 0);
}

// ---------------------------------------------------------------------------
// prep: fused input conversion.
// bid < 4096:  fp32 x -> bf16 X16, 8 elems/thread.
// bid >= 4096: fp32 W[k][n] -> bf16 WT[n][k], 32x32 LDS transpose tiles.
// ---------------------------------------------------------------------------
__global__ __launch_bounds__(256) void prep(const float* __restrict__ x, u16* __restrict__ X16,
                                            const float* __restrict__ w0, const float* __restrict__ w1,
                                            const float* __restrict__ w2, const float* __restrict__ w3,
                                            u16* __restrict__ o0, u16* __restrict__ o1,
                                            u16* __restrict__ o2, u16* __restrict__ o3) {
    __shared__ u16 t[32][33];
    int bid = blockIdx.x;
    if (bid < 4096) {
        int i = (bid * 256 + threadIdx.x) * 8;
        float4 v0 = *(const float4*)(x + i);
        float4 v1 = *(const float4*)(x + i + 4);
        ushort4 r0, r1;
        r0.x = f2bf(v0.x); r0.y = f2bf(v0.y); r0.z = f2bf(v0.z); r0.w = f2bf(v0.w);
        r1.x = f2bf(v1.x); r1.y = f2bf(v1.y); r1.z = f2bf(v1.z); r1.w = f2bf(v1.w);
        *(ushort4*)(X16 + i) = r0;
        *(ushort4*)(X16 + i + 4) = r1;
    } else {
        int lid = bid - 4096;
        int z = lid >> 10, r = lid & 1023;
        const float* w; u16* o;
        switch (z) {
            case 0: w = w0; o = o0; break;
            case 1: w = w1; o = o1; break;
            case 2: w = w2; o = o2; break;
            default: w = w3; o = o3; break;
        }
        int kb = (r >> 5) * 32, nb = (r & 31) * 32;
        int c = threadIdx.x & 31, r0 = threadIdx.x >> 5;
#pragma unroll
        for (int i = 0; i < 4; i++) {
            int rr = r0 + 8 * i;
            t[rr][c] = f2bf(w[(kb + rr) * D_ + nb + c]);
        }
        __syncthreads();
#pragma unroll
        for (int i = 0; i < 4; i++) {
            int rr = r0 + 8 * i;
            o[(nb + rr) * D_ + kb + c] = t[c][rr];
        }
    }
}

// ---------------------------------------------------------------------------
// R11 GEMM: m97-occupancy port of the verified R8 body.
// BM=BN=128, BK=32, 256 threads / 4 waves (2Mx2N, 64x64 per wave), TRIPLE
// buffer 48KB -> 3 blocks/CU (m97's 874-912 TF runs this tile at 3/CU: the
// cross-block TLP is what absorbs barrier drains -- our 600-TF variants all
// had <=2/CU). Counted vmcnt(4) (stage=4 instrs; leaves next stage in
// flight, guarantees 2-ahead landed), one s_barrier per K-tile, 2-ahead
// prefetch, T1 XCD panel-affinity, T2 XOR swizzle, T5 setprio.
// K-accumulation order identical (bitexact vs R8).
// ---------------------------------------------------------------------------
#define AB2_ (128 * 32)             // u16 per A region (8KB)
#define TB2_ (256 * 32)             // u16 per buffer (A + B, 16KB)
#define NKT_ 32                     // D_/32 K-tiles

__device__ __forceinline__ void gemm_body128(const u16* __restrict__ A,
                                             const u16* __restrict__ BT,
                                             const float* __restrict__ bias,
                                             void* __restrict__ Cout, int mode, float scale,
                                             u16* S, int nb, int mb) {
    int tid = threadIdx.x;
    int w = tid >> 6, lane = tid & 63, quad = lane >> 4, l16 = lane & 15;
    int wm = (w >> 1) * 64, wn = (w & 1) * 64;
    int x3 = l16 & 3;

    // staging source pointers (inverse-swizzled global, linear LDS dest)
    // A tile: 128 rows x 4x16B units = 512 units, 2/thread; B same.
    const u16* Aga[2]; const u16* Bga[2];
#pragma unroll
    for (int i = 0; i < 2; ++i) {
        int idx = i * 256 + tid, row = idx >> 2;
        int lu = (idx & 3) ^ (row & 3);
        Aga[i] = A + (size_t)(mb + row) * D_ + lu * 8;
        Bga[i] = BT + (size_t)(nb + row) * D_ + lu * 8;
    }

    facc4 acc[4][4] = {};

    u16* Bu0 = S;
    u16* Bu1 = S + TB2_;
    u16* Bu2 = S + 2 * TB2_;

    auto stage = [&](u16* Nb, int ko) {
#pragma unroll
        for (int i = 0; i < 2; ++i) gl_lds16(Aga[i] + ko, Nb + (i * 256 + tid) * 8);
#pragma unroll
        for (int i = 0; i < 2; ++i) gl_lds16(Bga[i] + ko, Nb + AB2_ + (i * 256 + tid) * 8);
    };
    auto compute = [&](const u16* Cb) {
        int pu = (quad ^ x3) * 8;                 // swizzled 16B-unit offset
        bfrag8 af[4], bf[4];
#pragma unroll
        for (int mt = 0; mt < 4; ++mt)
            af[mt] = *(const bfrag8*)(Cb + (wm + mt * 16 + l16) * 32 + pu);
#pragma unroll
        for (int nt = 0; nt < 4; ++nt)
            bf[nt] = *(const bfrag8*)(Cb + AB2_ + (wn + nt * 16 + l16) * 32 + pu);
        __builtin_amdgcn_s_setprio(1);
#pragma unroll
        for (int mt = 0; mt < 4; ++mt)
#pragma unroll
            for (int nt = 0; nt < 4; ++nt)
                acc[mt][nt] = __builtin_amdgcn_mfma_f32_16x16x32_bf16(af[mt], bf[nt], acc[mt][nt], 0, 0, 0);
        __builtin_amdgcn_s_setprio(0);
    };

    // prologue: stage tiles 0,1 (8 loads in flight per thread)
    stage(Bu0, 0);
    stage(Bu1, 32);

    u16 *bc = Bu0, *bn = Bu1, *bs = Bu2;
    for (int kt = 0; kt < NKT_; ++kt) {
        // counted wait: vmcnt(4) leaves stage(kt+1)'s 4 loads in flight but
        // guarantees stage(kt) landed (FIFO retirement). Never 0 mid-loop.
        if (kt < NKT_ - 1) asm volatile("s_waitcnt vmcnt(4)" ::: "memory");
        else               asm volatile("s_waitcnt vmcnt(0)" ::: "memory");
        __builtin_amdgcn_sched_barrier(0);
        __builtin_amdgcn_s_barrier();
        __builtin_amdgcn_sched_barrier(0);
        if (kt + 2 < NKT_) stage(bs, (kt + 2) * 32);
        compute(bc);
        u16* tmp = bc; bc = bn; bn = bs; bs = tmp;
    }

#pragma unroll
    for (int mt = 0; mt < 4; ++mt) {
        int m_base = mb + wm + mt * 16 + quad * 4;
#pragma unroll
        for (int nt = 0; nt < 4; ++nt) {
            int n = nb + wn + nt * 16 + l16;
            float bv = bias[n];
            int h = n >> 6, dd = n & 63;
#pragma unroll
            for (int r = 0; r < 4; ++r) {
                int m = m_base + r;
                float v = (acc[mt][nt][r] + bv) * scale;
                int bi = m >> 11, s = m & (S_ - 1);
                if (mode == 0) {
                    ((u16*)Cout)[(((bi * H_ + h) * S_) + s) * DH_ + dd] = bfr(v);
                } else if (mode == 1) {
                    ((u16*)Cout)[(((bi * H_ + h) * DH_) + dd) * S_ + s] = bfr(v);
                } else {
                    ((float*)Cout)[(size_t)m * D_ + n] = v;
                }
            }
        }
    }
}

#define CE_Q 0.18033688011112042f   // log2(e)/sqrt(DH), folded into Q

// 1536 blocks: xcd = lid&7; rest = lid>>3 in [0,192): z = rest/64,
// r2 = rest%64: m-panel = xcd*8 + (r2>>3) in [0,64), n = r2&7. Bijective;
// each XCD owns 8 contiguous m-panels for all n,z (A-panel L2 affinity).
__global__ __launch_bounds__(256, 3) void gemm_qkv(const u16* __restrict__ A,
                                                const u16* __restrict__ WTq, const float* __restrict__ bq, u16* __restrict__ Qb,
                                                const u16* __restrict__ WTk, const float* __restrict__ bk, u16* __restrict__ Kb,
                                                const u16* __restrict__ WTv, const float* __restrict__ bv, u16* __restrict__ VTb) {
    __shared__ __attribute__((aligned(16))) u16 Sh[3 * TB2_];   // 48 KiB
    int lid = blockIdx.x;
    int xcd = lid & 7, rest = lid >> 3;
    int z = rest >> 6, r2 = rest & 63;
    int mb = (xcd * 8 + (r2 >> 3)) * 128;
    int nb = (r2 & 7) * 128;
    switch (z) {
        case 0: gemm_body128(A, WTq, bq, Qb, 0, CE_Q, Sh, nb, mb); break;   // Q pre-scaled
        case 1: gemm_body128(A, WTk, bk, Kb, 0, 1.0f, Sh, nb, mb); break;
        default: gemm_body128(A, WTv, bv, VTb, 1, 1.0f, Sh, nb, mb); break;
    }
}

__global__ __launch_bounds__(256, 3) void gemm_o(const u16* __restrict__ A,
                                              const u16* __restrict__ WTo, const float* __restrict__ bo,
                                              float* __restrict__ out) {
    __shared__ __attribute__((aligned(16))) u16 Sh[3 * TB2_];   // 48 KiB
    int lid = blockIdx.x;
    int xcd = lid & 7, r2 = lid >> 3;          // r2 in [0,64)
    int mb = (xcd * 8 + (r2 >> 3)) * 128;
    int nb = (r2 & 7) * 128;
    gemm_body128(A, WTo, bo, out, 2, 1.0f, Sh, nb, mb);
}

// ---------------------------------------------------------------------------
// Flash attention, S^T/O^T formulation, fixed-base softmax.
// Block = 128 q-rows of one (b,h), 4 waves x 32 rows each.
// R11: KVBLK 64 staged as TWO 32-key HALVES processed sequentially with the
// unchanged (R10-verified) 32-key inner body -> halves barrier+loop overhead
// per key with IDENTICAL register footprint (st[2][2] reused per half; R9's
// KVBLK=64 spill came from st[2][4]+vf all live, avoided here).
// LDS 2buf x (K 8KB + V 8KB) = 32KB -> 4 blocks/CU. 2-buffer stage-ahead,
// ONE __syncthreads per 64 keys. Per-half data layout identical to R10's
// per-tile layout (same swizzle algebra). Balanced ci remap, bh-affinity
// XCD swizzle, in-kernel mask pack.
// ---------------------------------------------------------------------------
// exp2 + pack + lane-transpose (bpermute) + PV accumulate for one q-tile
__device__ __forceinline__ void soft_pv(const float* p, float& lp, facc4* oaccq,
                                        const bfrag8* vf, int a0, int a1, bool qlo) {
    float rs = 0.f;
    unsigned pk[4];
#pragma unroll
    for (int j = 0; j < 4; ++j) {
        float e0 = exp2f(p[2 * j]);
        float e1 = exp2f(p[2 * j + 1]);
        rs += e0; rs += e1;
        pk[j] = __builtin_amdgcn_perm(__float_as_uint(e1), __float_as_uint(e0), 0x07060302u);
    }
    lp += rs;                                   // per-lane partial; reduced once per chunk
    union { unsigned d[4]; bfrag8 v; } pb;
    {
        unsigned lo, hi;
        lo = __builtin_amdgcn_ds_bpermute(a0, (int)pk[0]);
        hi = __builtin_amdgcn_ds_bpermute(a0, (int)pk[2]);
        pb.d[0] = qlo ? lo : hi;
        lo = __builtin_amdgcn_ds_bpermute(a0, (int)pk[1]);
        hi = __builtin_amdgcn_ds_bpermute(a0, (int)pk[3]);
        pb.d[1] = qlo ? lo : hi;
        lo = __builtin_amdgcn_ds_bpermute(a1, (int)pk[0]);
        hi = __builtin_amdgcn_ds_bpermute(a1, (int)pk[2]);
        pb.d[2] = qlo ? lo : hi;
        lo = __builtin_amdgcn_ds_bpermute(a1, (int)pk[1]);
        hi = __builtin_amdgcn_ds_bpermute(a1, (int)pk[3]);
        pb.d[3] = qlo ? lo : hi;
    }
    __builtin_amdgcn_s_setprio(1);
#pragma unroll
    for (int dt = 0; dt < 4; ++dt)
        oaccq[dt] = __builtin_amdgcn_mfma_f32_16x16x32_bf16(vf[dt], pb.v, oaccq[dt], 0, 0, 0);
    __builtin_amdgcn_s_setprio(0);
}

__global__ __launch_bounds__(256, 4) void attn(const u16* __restrict__ Q,
                                               const u16* __restrict__ K,
                                               const u16* __restrict__ VT,
                                               const int* __restrict__ pm,
                                               u16* __restrict__ Aout) {
    __shared__ __attribute__((aligned(16))) u16 Ks[2][2][32 * 64]; // [buf][half] 4KB each
    __shared__ __attribute__((aligned(16))) u16 Vs[2][2][64 * 32]; // [buf][half] 4KB each
    __shared__ unsigned pms[64];                                   // packed pad mask

    int tid = threadIdx.x, w = tid >> 6, lane = tid & 63;
    int quad = lane >> 4, l16 = lane & 15;

    // lid -> (bh, ci): all 16 blocks of one bh share lid&7 (same XCD L2).
    int lid = blockIdx.x;                       // [0,1024)
    int bh  = (lid & 7) * 8 + ((lid >> 3) & 7); // [0,64)
    int g   = lid >> 6;                         // [0,16) chunk group
    int gq = g >> 2, gr = g & 3;                // balanced ci remap
    int ci = (gq == 0) ? 15 - gr : (gq == 1) ? gr : (gq == 2) ? 11 - gr : 4 + gr;
    int b = bh >> 4, h = bh & 15;

    int qbase = ci * 128;
    int qw = qbase + w * 32;                    // this wave's 32 q-rows
    int tmax = (qbase >> 6) + 1;                // 64-key tiles 0..tmax (= 2ci+1)

    const u16* Qp = Q + (size_t)(b * H_ + h) * S_ * DH_;
    const u16* Kp = K + (size_t)(b * H_ + h) * S_ * DH_;
    const u16* Vp = VT + (size_t)(b * H_ + h) * DH_ * S_;
    u16* Ao = Aout + (size_t)b * S_ * D_ + h * DH_;

    // build padding bitmask: wave w covers words w*16..w*16+15 (2 per ballot)
#pragma unroll
    for (int i = 0; i < 8; ++i) {
        int j2 = w * 16 + i * 2;
        u64 m = __ballot(pm[b * S_ + j2 * 32 + lane] != 0);
        if (lane == 0) { pms[j2] = (unsigned)m; pms[j2 + 1] = (unsigned)(m >> 32); }
    }

    // staging thread map (inverse-swizzled global source, linear LDS dest)
    int krow = tid >> 3, ku = tid & 7;          // K half: 32 rows x 8x16B units
    const u16* Kg = Kp + krow * DH_ + ((ku ^ (krow & 7)) * 8);
    int vrow = tid >> 2, vu = tid & 3;          // V half: 64 rows x 4x16B units
    const u16* Vg = Vp + vrow * S_ + ((vu ^ (vrow & 3)) * 8);

    // swizzled read constants
    int k7 = l16 & 7, v3 = l16 & 3;

    // bpermute byte-addresses for the P^T lane permute (loop-invariant)
    int a0 = ((((2 * quad) & 3) * 16 + l16) << 2);
    int a1 = ((((2 * quad + 1) & 3) * 16 + l16) << 2);
    bool qlo = quad < 2;

    bfrag8 qf[2][2];
#pragma unroll
    for (int qt = 0; qt < 2; ++qt)
#pragma unroll
        for (int cc = 0; cc < 2; ++cc)
            qf[qt][cc] = *(const bfrag8*)(Qp + (qw + qt * 16 + l16) * DH_ + cc * 32 + quad * 8);

    facc4 oacc[2][4] = {};                      // O^T: [qt][dt], row=d, col=q=l16
    float lp[2] = {0.f, 0.f};                   // per-lane partial denominators

    // prologue: stage 64-key tile 0 (both halves) into buffer 0
    gl_lds16(Kg, &Ks[0][0][tid * 8]);
    gl_lds16(Kg + 32 * DH_, &Ks[0][1][tid * 8]);
    gl_lds16(Vg, &Vs[0][0][tid * 8]);
    gl_lds16(Vg + 32, &Vs[0][1][tid * 8]);
    __syncthreads();                            // drains vmcnt; tile 0 + pms ready

    for (int t = 0; t <= tmax; ++t) {
        int cur = t & 1, nxt = cur ^ 1;
        if (t < tmax) {                         // issue next-tile stage FIRST
            int k1 = (t + 1) * 64;
            gl_lds16(Kg + k1 * DH_, &Ks[nxt][0][tid * 8]);
            gl_lds16(Kg + (k1 + 32) * DH_, &Ks[nxt][1][tid * 8]);
            gl_lds16(Vg + k1, &Vs[nxt][0][tid * 8]);
            gl_lds16(Vg + k1 + 32, &Vs[nxt][1][tid * 8]);
        }

#pragma unroll
        for (int s = 0; s < 2; ++s) {           // two 32-key halves, R10 body each
            int k0 = t * 64 + s * 32;
            const u16* Kc = Ks[cur][s];
            const u16* Vc = Vs[cur][s];
            unsigned vm = pms[2 * t + s];

            // K fragments from LDS (swizzled read)
            bfrag8 kf00 = *(const bfrag8*)(Kc + (l16 * 8        + ((quad)     ^ k7)) * 8);
            bfrag8 kf01 = *(const bfrag8*)(Kc + (l16 * 8        + ((quad + 4) ^ k7)) * 8);
            bfrag8 kf10 = *(const bfrag8*)(Kc + ((l16 + 16) * 8 + ((quad)     ^ k7)) * 8);
            bfrag8 kf11 = *(const bfrag8*)(Kc + ((l16 + 16) * 8 + ((quad + 4) ^ k7)) * 8);
            bfrag8 vf[4];
#pragma unroll
            for (int dt = 0; dt < 4; ++dt)
                vf[dt] = *(const bfrag8*)(Vc + ((dt * 16 + l16) * 4 + (quad ^ v3)) * 8);

            facc4 st[2][2] = {};                // S^T (pre-scaled): row=key, col=q
            __builtin_amdgcn_s_setprio(1);
#pragma unroll
            for (int qt = 0; qt < 2; ++qt) {
                st[qt][0] = __builtin_amdgcn_mfma_f32_16x16x32_bf16(kf00, qf[qt][0], st[qt][0], 0, 0, 0);
                st[qt][0] = __builtin_amdgcn_mfma_f32_16x16x32_bf16(kf01, qf[qt][1], st[qt][0], 0, 0, 0);
                st[qt][1] = __builtin_amdgcn_mfma_f32_16x16x32_bf16(kf10, qf[qt][0], st[qt][1], 0, 0, 0);
                st[qt][1] = __builtin_amdgcn_mfma_f32_16x16x32_bf16(kf11, qf[qt][1], st[qt][1], 0, 0, 0);
            }
            __builtin_amdgcn_s_setprio(0);

            if (vm == 0xffffffffu && k0 + 31 < qw) {
                // interior, fully valid: zero mask VALU
#pragma unroll
                for (int qt = 0; qt < 2; ++qt) {
                    float p[8];
#pragma unroll
                    for (int kt = 0; kt < 2; ++kt)
#pragma unroll
                        for (int r = 0; r < 4; ++r) p[kt * 4 + r] = st[qt][kt][r];
                    soft_pv(p, lp[qt], oacc[qt], vf, a0, a1, qlo);
                }
            } else {
                // diagonal / padded / above-diagonal: per-element mask
#pragma unroll
                for (int qt = 0; qt < 2; ++qt) {
                    int q0 = qw + qt * 16;
                    float p[8];
#pragma unroll
                    for (int kt = 0; kt < 2; ++kt)
#pragma unroll
                        for (int r = 0; r < 4; ++r) {
                            int kl = kt * 16 + quad * 4 + r;
                            bool ok = ((vm >> kl) & 1u) && (k0 + kl <= q0 + l16);
                            p[kt * 4 + r] = ok ? st[qt][kt][r] : -1e30f;
                        }
                    soft_pv(p, lp[qt], oacc[qt], vf, a0, a1, qlo);
                }
            }
        }
        __syncthreads();                        // next tile landed; cur free
    }

    // finalize: reduce l across quads, normalize, store O^T
#pragma unroll
    for (int qt = 0; qt < 2; ++qt) {
        float l = lp[qt];
        l += __shfl_xor(l, 16);
        l += __shfl_xor(l, 32);
        float linv = (l > 0.f) ? 1.f / l : 0.f;
        size_t qoff = (size_t)(qw + qt * 16 + l16) * D_;
#pragma unroll
        for (int dt = 0; dt < 4; ++dt) {
            union { u16 hh[4]; u64 q; } pk4;
#pragma unroll
            for (int r = 0; r < 4; ++r) pk4.hh[r] = bfr(oacc[qt][dt][r] * linv);
            *(u64*)(Ao + qoff + dt * 16 + quad * 4) = pk4.q;
        }
    }
}

// ---------------------------------------------------------------------------
extern "C" void kernel_launch(void* const* d_in, const int* in_sizes, int n_in,
                              void* d_out, int out_size, void* d_ws, size_t ws_size,
                              hipStream_t stream) {
    const float* x  = (const float*)d_in[0];
    const float* Wq = (const float*)d_in[1];
    const float* bq = (const float*)d_in[2];
    const float* Wk = (const float*)d_in[3];
    const float* bk = (const float*)d_in[4];
    const float* Wv = (const float*)d_in[5];
    const float* bv = (const float*)d_in[6];
    const float* Wo = (const float*)d_in[7];
    const float* bo = (const float*)d_in[8];
    const int*   pm = (const int*)d_in[9];
    float* out = (float*)d_out;

    char* ws = (char*)d_ws;
    const size_t SZ_XD = (size_t)M_ * D_ * 2;   // 16 MiB bf16 [M,D]
    const size_t SZ_W  = (size_t)D_ * D_ * 2;   //  2 MiB bf16 [D,D]
    u16* X16 = (u16*)ws;                 // reused as attended output (safe: X16's
                                         // last read is the V GEMM; attn writes later)
    u16* WTq = (u16*)(ws + SZ_XD);
    u16* WTk = (u16*)(ws + SZ_XD + SZ_W);
    u16* WTv = (u16*)(ws + SZ_XD + 2 * SZ_W);
    u16* WTo = (u16*)(ws + SZ_XD + 3 * SZ_W);
    u16* Qb  = (u16*)(ws + SZ_XD + 4 * SZ_W);
    u16* Kb  = (u16*)(ws + 2 * SZ_XD + 4 * SZ_W);
    u16* VTb = (u16*)(ws + 3 * SZ_XD + 4 * SZ_W);
    u16* Att = X16;

    prep<<<dim3(8192), 256, 0, stream>>>(x, X16, Wq, Wk, Wv, Wo, WTq, WTk, WTv, WTo);

    gemm_qkv<<<dim3(1536), 256, 0, stream>>>(X16, WTq, bq, Qb, WTk, bk, Kb, WTv, bv, VTb);

    attn<<<dim3(1024), 256, 0, stream>>>(Qb, Kb, VTb, pm, Att);

    gemm_o<<<dim3(512), 256, 0, stream>>>(Att, WTo, bo, out);
}

// Round 13
// 257.785 us; speedup vs baseline: 1.1375x; 1.1375x over previous
//
#include <hip/hip_runtime.h>
#include <hip/hip_bf16.h>

#define B_   4
#define S_   2048
#define D_   1024
#define H_   16
#define DH_  64
#define M_   (B_ * S_)

typedef __attribute__((ext_vector_type(8))) short  bfrag8;   // 8 bf16 = 4 VGPRs
typedef __attribute__((ext_vector_type(4))) float  facc4;    // 4 fp32 accum
typedef unsigned short u16;
typedef unsigned long long u64;

__device__ __forceinline__ u16 f2bf(float f) {
    union { __hip_bfloat16 h; u16 u; } c;
    c.h = __float2bfloat16(f);
    return c.u;
}

// manual RNE fp32->bf16 (finite inputs only)
__device__ __forceinline__ u16 bfr(float f) {
    unsigned b = __float_as_uint(f);
    return (u16)((b + 0x7FFFu + ((b >> 16) & 1u)) >> 16);
}

// async global->LDS, 16B per lane; LDS dest must be wave-uniform base + lane*16
__device__ __forceinline__ void gl_lds16(const u16* g, u16* l) {
    __builtin_amdgcn_global_load_lds((const __attribute__((address_space(1))) void*)g,
                                     (__attribute__((address_space(3))) void*)l,
                                     16, 0, 0);
}

// ---------------------------------------------------------------------------
// prep: fused input conversion.
// bid < 4096:  fp32 x -> bf16 X16, 8 elems/thread.
// bid >= 4096: fp32 W[k][n] -> bf16 WT[n][k], 32x32 LDS transpose tiles.
// ---------------------------------------------------------------------------
__global__ __launch_bounds__(256) void prep(const float* __restrict__ x, u16* __restrict__ X16,
                                            const float* __restrict__ w0, const float* __restrict__ w1,
                                            const float* __restrict__ w2, const float* __restrict__ w3,
                                            u16* __restrict__ o0, u16* __restrict__ o1,
                                            u16* __restrict__ o2, u16* __restrict__ o3) {
    __shared__ u16 t[32][33];
    int bid = blockIdx.x;
    if (bid < 4096) {
        int i = (bid * 256 + threadIdx.x) * 8;
        float4 v0 = *(const float4*)(x + i);
        float4 v1 = *(const float4*)(x + i + 4);
        ushort4 r0, r1;
        r0.x = f2bf(v0.x); r0.y = f2bf(v0.y); r0.z = f2bf(v0.z); r0.w = f2bf(v0.w);
        r1.x = f2bf(v1.x); r1.y = f2bf(v1.y); r1.z = f2bf(v1.z); r1.w = f2bf(v1.w);
        *(ushort4*)(X16 + i) = r0;
        *(ushort4*)(X16 + i + 4) = r1;
    } else {
        int lid = bid - 4096;
        int z = lid >> 10, r = lid & 1023;
        const float* w; u16* o;
        switch (z) {
            case 0: w = w0; o = o0; break;
            case 1: w = w1; o = o1; break;
            case 2: w = w2; o = o2; break;
            default: w = w3; o = o3; break;
        }
        int kb = (r >> 5) * 32, nb = (r & 31) * 32;
        int c = threadIdx.x & 31, r0 = threadIdx.x >> 5;
#pragma unroll
        for (int i = 0; i < 4; i++) {
            int rr = r0 + 8 * i;
            t[rr][c] = f2bf(w[(kb + rr) * D_ + nb + c]);
        }
        __syncthreads();
#pragma unroll
        for (int i = 0; i < 4; i++) {
            int rr = r0 + 8 * i;
            o[(nb + rr) * D_ + kb + c] = t[c][rr];
        }
    }
}

// ---------------------------------------------------------------------------
// R8 GEMM (best measured): C[M,N] = (A[M,K] @ BT[N,K]^T + bias) * scale.
// BM=256 x BN=128 x BK=32, 512 threads / 8 waves, tri-buffer 72KB ->
// 2 blocks/CU, counted vmcnt(3), one s_barrier per K-tile, 2-ahead prefetch.
// T1 XCD panel-affinity, T2 2-bit XOR swizzle, T5 setprio.
// ---------------------------------------------------------------------------
#define ABUF_ (256 * 32)            // u16 per A region (16KB)
#define TBUF_ ((256 + 128) * 32)    // u16 per buffer (A + B, 24KB)
#define NKT_  32                    // D_/32 K-tiles

__device__ __forceinline__ void gemm_body256(const u16* __restrict__ A,
                                             const u16* __restrict__ BT,
                                             const float* __restrict__ bias,
                                             void* __restrict__ Cout, int mode, float scale,
                                             u16* S, int nb, int mb) {
    int tid = threadIdx.x;
    int w = tid >> 6, lane = tid & 63, quad = lane >> 4, l16 = lane & 15;
    int wm = (w >> 1) * 64, wn = (w & 1) * 64;
    int x3 = l16 & 3;

    // staging source pointers (inverse-swizzled global, linear LDS dest)
    const u16* Aga[2]; const u16* Bga;
#pragma unroll
    for (int i = 0; i < 2; ++i) {
        int idx = i * 512 + tid, row = idx >> 2;
        int lu = (idx & 3) ^ (row & 3);
        Aga[i] = A + (size_t)(mb + row) * D_ + lu * 8;
    }
    {
        int row = tid >> 2;
        int lu = (tid & 3) ^ (row & 3);
        Bga = BT + (size_t)(nb + row) * D_ + lu * 8;
    }

    facc4 acc[4][4] = {};

    u16* Bu0 = S;
    u16* Bu1 = S + TBUF_;
    u16* Bu2 = S + 2 * TBUF_;

    auto stage = [&](u16* Nb, int ko) {
#pragma unroll
        for (int i = 0; i < 2; ++i) gl_lds16(Aga[i] + ko, Nb + (i * 512 + tid) * 8);
        gl_lds16(Bga + ko, Nb + ABUF_ + tid * 8);
    };
    auto compute = [&](const u16* Cb) {
        int pu = (quad ^ x3) * 8;                 // swizzled 16B-unit offset
        bfrag8 af[4], bf[4];
#pragma unroll
        for (int mt = 0; mt < 4; ++mt)
            af[mt] = *(const bfrag8*)(Cb + (wm + mt * 16 + l16) * 32 + pu);
#pragma unroll
        for (int nt = 0; nt < 4; ++nt)
            bf[nt] = *(const bfrag8*)(Cb + ABUF_ + (wn + nt * 16 + l16) * 32 + pu);
        __builtin_amdgcn_s_setprio(1);
#pragma unroll
        for (int mt = 0; mt < 4; ++mt)
#pragma unroll
            for (int nt = 0; nt < 4; ++nt)
                acc[mt][nt] = __builtin_amdgcn_mfma_f32_16x16x32_bf16(af[mt], bf[nt], acc[mt][nt], 0, 0, 0);
        __builtin_amdgcn_s_setprio(0);
    };

    // prologue: stage tiles 0,1
    stage(Bu0, 0);
    stage(Bu1, 32);

    u16 *bc = Bu0, *bn = Bu1, *bs = Bu2;
    for (int kt = 0; kt < NKT_; ++kt) {
        if (kt < NKT_ - 1) asm volatile("s_waitcnt vmcnt(3)" ::: "memory");
        else               asm volatile("s_waitcnt vmcnt(0)" ::: "memory");
        __builtin_amdgcn_sched_barrier(0);
        __builtin_amdgcn_s_barrier();
        __builtin_amdgcn_sched_barrier(0);
        if (kt + 2 < NKT_) stage(bs, (kt + 2) * 32);
        compute(bc);
        u16* tmp = bc; bc = bn; bn = bs; bs = tmp;
    }

#pragma unroll
    for (int mt = 0; mt < 4; ++mt) {
        int m_base = mb + wm + mt * 16 + quad * 4;
#pragma unroll
        for (int nt = 0; nt < 4; ++nt) {
            int n = nb + wn + nt * 16 + l16;
            float bv = bias[n];
            int h = n >> 6, dd = n & 63;
#pragma unroll
            for (int r = 0; r < 4; ++r) {
                int m = m_base + r;
                float v = (acc[mt][nt][r] + bv) * scale;
                int bi = m >> 11, s = m & (S_ - 1);
                if (mode == 0) {
                    ((u16*)Cout)[(((bi * H_ + h) * S_) + s) * DH_ + dd] = bfr(v);
                } else if (mode == 1) {
                    ((u16*)Cout)[(((bi * H_ + h) * DH_) + dd) * S_ + s] = bfr(v);
                } else {
                    ((float*)Cout)[(size_t)m * D_ + n] = v;
                }
            }
        }
    }
}

#define CE_Q 0.18033688011112042f   // log2(e)/sqrt(DH), folded into Q

// 1D grid (768): xcd = lid&7, s = lid>>3 in [0,96); z = s>>5 selects weight;
// inner = s&31: y = xcd*4 + (inner>>3) in [0,32), x = inner&7. Bijective.
__global__ __launch_bounds__(512, 4) void gemm_qkv(const u16* __restrict__ A,
                                                const u16* __restrict__ WTq, const float* __restrict__ bq, u16* __restrict__ Qb,
                                                const u16* __restrict__ WTk, const float* __restrict__ bk, u16* __restrict__ Kb,
                                                const u16* __restrict__ WTv, const float* __restrict__ bv, u16* __restrict__ VTb) {
    __shared__ __attribute__((aligned(16))) u16 Sh[3 * TBUF_];   // 72 KiB
    int lid = blockIdx.x;
    int xcd = lid & 7, s = lid >> 3;
    int z = s >> 5, inner = s & 31;
    int mb = (xcd * 4 + (inner >> 3)) * 256;
    int nb = (inner & 7) * 128;
    switch (z) {
        case 0: gemm_body256(A, WTq, bq, Qb, 0, CE_Q, Sh, nb, mb); break;   // Q pre-scaled
        case 1: gemm_body256(A, WTk, bk, Kb, 0, 1.0f, Sh, nb, mb); break;
        default: gemm_body256(A, WTv, bv, VTb, 1, 1.0f, Sh, nb, mb); break;
    }
}

__global__ __launch_bounds__(512, 4) void gemm_o(const u16* __restrict__ A,
                                              const u16* __restrict__ WTo, const float* __restrict__ bo,
                                              float* __restrict__ out) {
    __shared__ __attribute__((aligned(16))) u16 Sh[3 * TBUF_];   // 72 KiB
    int lid = blockIdx.x;
    int xcd = lid & 7, s = lid >> 3;           // s in [0,32)
    int mb = (xcd * 4 + (s >> 3)) * 256;
    int nb = (s & 7) * 128;
    gemm_body256(A, WTo, bo, out, 2, 1.0f, Sh, nb, mb);
}

// ---------------------------------------------------------------------------
// Flash attention, S^T/O^T formulation, fixed-base softmax (best measured).
// KVBLK=32, 2-buffer stage-ahead, ONE __syncthreads/iter, no skip branch,
// in-kernel mask pack, balanced ci remap, bh-affinity XCD swizzle.
// (R9 KVBLK=64 and R11 half-split both regressed via scratch traffic;
// R7 counted-vmcnt regressed: cross-block TLP already absorbs the drain.)
// ---------------------------------------------------------------------------
// exp2 + pack + lane-transpose (bpermute) + PV accumulate for one q-tile
__device__ __forceinline__ void soft_pv(const float* p, float& lp, facc4* oaccq,
                                        const bfrag8* vf, int a0, int a1, bool qlo) {
    float rs = 0.f;
    unsigned pk[4];
#pragma unroll
    for (int j = 0; j < 4; ++j) {
        float e0 = exp2f(p[2 * j]);
        float e1 = exp2f(p[2 * j + 1]);
        rs += e0; rs += e1;
        pk[j] = __builtin_amdgcn_perm(__float_as_uint(e1), __float_as_uint(e0), 0x07060302u);
    }
    lp += rs;                                   // per-lane partial; reduced once per chunk
    union { unsigned d[4]; bfrag8 v; } pb;
    {
        unsigned lo, hi;
        lo = __builtin_amdgcn_ds_bpermute(a0, (int)pk[0]);
        hi = __builtin_amdgcn_ds_bpermute(a0, (int)pk[2]);
        pb.d[0] = qlo ? lo : hi;
        lo = __builtin_amdgcn_ds_bpermute(a0, (int)pk[1]);
        hi = __builtin_amdgcn_ds_bpermute(a0, (int)pk[3]);
        pb.d[1] = qlo ? lo : hi;
        lo = __builtin_amdgcn_ds_bpermute(a1, (int)pk[0]);
        hi = __builtin_amdgcn_ds_bpermute(a1, (int)pk[2]);
        pb.d[2] = qlo ? lo : hi;
        lo = __builtin_amdgcn_ds_bpermute(a1, (int)pk[1]);
        hi = __builtin_amdgcn_ds_bpermute(a1, (int)pk[3]);
        pb.d[3] = qlo ? lo : hi;
    }
    __builtin_amdgcn_s_setprio(1);
#pragma unroll
    for (int dt = 0; dt < 4; ++dt)
        oaccq[dt] = __builtin_amdgcn_mfma_f32_16x16x32_bf16(vf[dt], pb.v, oaccq[dt], 0, 0, 0);
    __builtin_amdgcn_s_setprio(0);
}

__global__ __launch_bounds__(256, 4) void attn(const u16* __restrict__ Q,
                                               const u16* __restrict__ K,
                                               const u16* __restrict__ VT,
                                               const int* __restrict__ pm,
                                               u16* __restrict__ Aout) {
    __shared__ __attribute__((aligned(16))) u16 Ks[2][32 * 64];   // [key][dh] 4KB x2
    __shared__ __attribute__((aligned(16))) u16 Vs[2][64 * 32];   // [d][key] 4KB x2
    __shared__ unsigned pms[64];                                  // packed pad mask

    int tid = threadIdx.x, w = tid >> 6, lane = tid & 63;
    int quad = lane >> 4, l16 = lane & 15;

    // lid -> (bh, ci): all 16 blocks of one bh share lid&7 (same XCD L2).
    int lid = blockIdx.x;                       // [0,1024)
    int bh  = (lid & 7) * 8 + ((lid >> 3) & 7); // [0,64)
    int g   = lid >> 6;                         // [0,16) chunk group
    int gq = g >> 2, gr = g & 3;                // balanced ci remap
    int ci = (gq == 0) ? 15 - gr : (gq == 1) ? gr : (gq == 2) ? 11 - gr : 4 + gr;
    int b = bh >> 4, h = bh & 15;

    int qbase = ci * 128;
    int qw = qbase + w * 32;                    // this wave's 32 q-rows
    int tmax = (qbase >> 5) + 3;                // tiles 0..tmax (32 keys each)

    const u16* Qp = Q + (size_t)(b * H_ + h) * S_ * DH_;
    const u16* Kp = K + (size_t)(b * H_ + h) * S_ * DH_;
    const u16* Vp = VT + (size_t)(b * H_ + h) * DH_ * S_;
    u16* Ao = Aout + (size_t)b * S_ * D_ + h * DH_;

    // build padding bitmask: wave w covers words w*16..w*16+15 (2 per ballot)
#pragma unroll
    for (int i = 0; i < 8; ++i) {
        int j2 = w * 16 + i * 2;
        u64 m = __ballot(pm[b * S_ + j2 * 32 + lane] != 0);
        if (lane == 0) { pms[j2] = (unsigned)m; pms[j2 + 1] = (unsigned)(m >> 32); }
    }

    // staging thread map (inverse-swizzled global source, linear LDS dest)
    int krow = tid >> 3, ku = tid & 7;          // K tile: 32 rows x 8x16B units
    const u16* Kg = Kp + krow * DH_ + ((ku ^ (krow & 7)) * 8);
    int vrow = tid >> 2, vu = tid & 3;          // V tile: 64 rows x 4x16B units
    const u16* Vg = Vp + vrow * S_ + ((vu ^ (vrow & 3)) * 8);
    u16* Kl[2] = { &Ks[0][tid * 8], &Ks[1][tid * 8] };
    u16* Vl[2] = { &Vs[0][tid * 8], &Vs[1][tid * 8] };

    // swizzled read constants
    int k7 = l16 & 7, v3 = l16 & 3;

    // bpermute byte-addresses for the P^T lane permute (loop-invariant)
    int a0 = ((((2 * quad) & 3) * 16 + l16) << 2);
    int a1 = ((((2 * quad + 1) & 3) * 16 + l16) << 2);
    bool qlo = quad < 2;

    bfrag8 qf[2][2];
#pragma unroll
    for (int qt = 0; qt < 2; ++qt)
#pragma unroll
        for (int cc = 0; cc < 2; ++cc)
            qf[qt][cc] = *(const bfrag8*)(Qp + (qw + qt * 16 + l16) * DH_ + cc * 32 + quad * 8);

    facc4 oacc[2][4] = {};                      // O^T: [qt][dt], row=d, col=q=l16
    float lp[2] = {0.f, 0.f};                   // per-lane partial denominators

    // prologue: stage tile 0 into buffer 0
    gl_lds16(Kg, Kl[0]);
    gl_lds16(Vg, Vl[0]);
    __syncthreads();                            // drains vmcnt; tile 0 + pms ready
    unsigned vmn = pms[0];

    for (int t = 0; t <= tmax; ++t) {
        int cur = t & 1, nxt = cur ^ 1;
        unsigned vm = vmn;
        if (t < tmax) {                         // issue next-tile stage FIRST
            int k1 = (t + 1) * 32;
            gl_lds16(Kg + k1 * DH_, Kl[nxt]);
            gl_lds16(Vg + k1, Vl[nxt]);
            vmn = pms[t + 1];
        }
        int k0 = t * 32;
        const u16* Kc = Ks[cur];
        const u16* Vc = Vs[cur];

        // K fragments from LDS (swizzled read)
        bfrag8 kf00 = *(const bfrag8*)(Kc + (l16 * 8        + ((quad)     ^ k7)) * 8);
        bfrag8 kf01 = *(const bfrag8*)(Kc + (l16 * 8        + ((quad + 4) ^ k7)) * 8);
        bfrag8 kf10 = *(const bfrag8*)(Kc + ((l16 + 16) * 8 + ((quad)     ^ k7)) * 8);
        bfrag8 kf11 = *(const bfrag8*)(Kc + ((l16 + 16) * 8 + ((quad + 4) ^ k7)) * 8);
        bfrag8 vf[4];
#pragma unroll
        for (int dt = 0; dt < 4; ++dt)
            vf[dt] = *(const bfrag8*)(Vc + ((dt * 16 + l16) * 4 + (quad ^ v3)) * 8);

        facc4 st[2][2] = {};                    // S^T (pre-scaled): row=key, col=q
        __builtin_amdgcn_s_setprio(1);
#pragma unroll
        for (int qt = 0; qt < 2; ++qt) {
            st[qt][0] = __builtin_amdgcn_mfma_f32_16x16x32_bf16(kf00, qf[qt][0], st[qt][0], 0, 0, 0);
            st[qt][0] = __builtin_amdgcn_mfma_f32_16x16x32_bf16(kf01, qf[qt][1], st[qt][0], 0, 0, 0);
            st[qt][1] = __builtin_amdgcn_mfma_f32_16x16x32_bf16(kf10, qf[qt][0], st[qt][1], 0, 0, 0);
            st[qt][1] = __builtin_amdgcn_mfma_f32_16x16x32_bf16(kf11, qf[qt][1], st[qt][1], 0, 0, 0);
        }
        __builtin_amdgcn_s_setprio(0);

        if (vm == 0xffffffffu && k0 + 31 < qw) {
            // interior, fully valid: zero mask VALU
#pragma unroll
            for (int qt = 0; qt < 2; ++qt) {
                float p[8];
#pragma unroll
                for (int kt = 0; kt < 2; ++kt)
#pragma unroll
                    for (int r = 0; r < 4; ++r) p[kt * 4 + r] = st[qt][kt][r];
                soft_pv(p, lp[qt], oacc[qt], vf, a0, a1, qlo);
            }
        } else {
            // diagonal / padded / above-diagonal tile: per-element mask
#pragma unroll
            for (int qt = 0; qt < 2; ++qt) {
                int q0 = qw + qt * 16;
                float p[8];
#pragma unroll
                for (int kt = 0; kt < 2; ++kt)
#pragma unroll
                    for (int r = 0; r < 4; ++r) {
                        int kl = kt * 16 + quad * 4 + r;
                        bool ok = ((vm >> kl) & 1u) && (k0 + kl <= q0 + l16);
                        p[kt * 4 + r] = ok ? st[qt][kt][r] : -1e30f;
                    }
                soft_pv(p, lp[qt], oacc[qt], vf, a0, a1, qlo);
            }
        }
        __syncthreads();                        // next tile landed; cur free
    }

    // finalize: reduce l across quads, normalize, store O^T
#pragma unroll
    for (int qt = 0; qt < 2; ++qt) {
        float l = lp[qt];
        l += __shfl_xor(l, 16);
        l += __shfl_xor(l, 32);
        float linv = (l > 0.f) ? 1.f / l : 0.f;
        size_t qoff = (size_t)(qw + qt * 16 + l16) * D_;
#pragma unroll
        for (int dt = 0; dt < 4; ++dt) {
            union { u16 hh[4]; u64 q; } pk4;
#pragma unroll
            for (int r = 0; r < 4; ++r) pk4.hh[r] = bfr(oacc[qt][dt][r] * linv);
            *(u64*)(Ao + qoff + dt * 16 + quad * 4) = pk4.q;
        }
    }
}

// ---------------------------------------------------------------------------
extern "C" void kernel_launch(void* const* d_in, const int* in_sizes, int n_in,
                              void* d_out, int out_size, void* d_ws, size_t ws_size,
                              hipStream_t stream) {
    const float* x  = (const float*)d_in[0];
    const float* Wq = (const float*)d_in[1];
    const float* bq = (const float*)d_in[2];
    const float* Wk = (const float*)d_in[3];
    const float* bk = (const float*)d_in[4];
    const float* Wv = (const float*)d_in[5];
    const float* bv = (const float*)d_in[6];
    const float* Wo = (const float*)d_in[7];
    const float* bo = (const float*)d_in[8];
    const int*   pm = (const int*)d_in[9];
    float* out = (float*)d_out;

    char* ws = (char*)d_ws;
    const size_t SZ_XD = (size_t)M_ * D_ * 2;   // 16 MiB bf16 [M,D]
    const size_t SZ_W  = (size_t)D_ * D_ * 2;   //  2 MiB bf16 [D,D]
    u16* X16 = (u16*)ws;                 // reused as attended output (safe: X16's
                                         // last read is the V GEMM; attn writes later)
    u16* WTq = (u16*)(ws + SZ_XD);
    u16* WTk = (u16*)(ws + SZ_XD + SZ_W);
    u16* WTv = (u16*)(ws + SZ_XD + 2 * SZ_W);
    u16* WTo = (u16*)(ws + SZ_XD + 3 * SZ_W);
    u16* Qb  = (u16*)(ws + SZ_XD + 4 * SZ_W);
    u16* Kb  = (u16*)(ws + 2 * SZ_XD + 4 * SZ_W);
    u16* VTb = (u16*)(ws + 3 * SZ_XD + 4 * SZ_W);
    u16* Att = X16;

    prep<<<dim3(8192), 256, 0, stream>>>(x, X16, Wq, Wk, Wv, Wo, WTq, WTk, WTv, WTo);

    gemm_qkv<<<dim3(768), 512, 0, stream>>>(X16, WTq, bq, Qb, WTk, bk, Kb, WTv, bv, VTb);

    attn<<<dim3(1024), 256, 0, stream>>>(Qb, Kb, VTb, pm, Att);

    gemm_o<<<dim3(256), 512, 0, stream>>>(Att, WTo, bo, out);
}

// Round 14
// 256.062 us; speedup vs baseline: 1.1451x; 1.0067x over previous
//
#include <hip/hip_runtime.h>
#include <hip/hip_bf16.h>

#define B_   4
#define S_   2048
#define D_   1024
#define H_   16
#define DH_  64
#define M_   (B_ * S_)

typedef __attribute__((ext_vector_type(8))) short  bfrag8;   // 8 bf16 = 4 VGPRs
typedef __attribute__((ext_vector_type(4))) float  facc4;    // 4 fp32 accum
typedef unsigned short u16;
typedef unsigned long long u64;

__device__ __forceinline__ u16 f2bf(float f) {
    union { __hip_bfloat16 h; u16 u; } c;
    c.h = __float2bfloat16(f);
    return c.u;
}

// manual RNE fp32->bf16 (finite inputs only)
__device__ __forceinline__ u16 bfr(float f) {
    unsigned b = __float_as_uint(f);
    return (u16)((b + 0x7FFFu + ((b >> 16) & 1u)) >> 16);
}

// async global->LDS, 16B per lane; LDS dest must be wave-uniform base + lane*16
__device__ __forceinline__ void gl_lds16(const u16* g, u16* l) {
    __builtin_amdgcn_global_load_lds((const __attribute__((address_space(1))) void*)g,
                                     (__attribute__((address_space(3))) void*)l,
                                     16, 0, 0);
}

// ---------------------------------------------------------------------------
// prep: fused input conversion.
// bid < 4096:  fp32 x -> bf16 X16, 8 elems/thread.
// bid >= 4096: fp32 W[k][n] -> bf16 WT[n][k], 32x32 LDS transpose tiles.
// ---------------------------------------------------------------------------
__global__ __launch_bounds__(256) void prep(const float* __restrict__ x, u16* __restrict__ X16,
                                            const float* __restrict__ w0, const float* __restrict__ w1,
                                            const float* __restrict__ w2, const float* __restrict__ w3,
                                            u16* __restrict__ o0, u16* __restrict__ o1,
                                            u16* __restrict__ o2, u16* __restrict__ o3) {
    __shared__ u16 t[32][33];
    int bid = blockIdx.x;
    if (bid < 4096) {
        int i = (bid * 256 + threadIdx.x) * 8;
        float4 v0 = *(const float4*)(x + i);
        float4 v1 = *(const float4*)(x + i + 4);
        ushort4 r0, r1;
        r0.x = f2bf(v0.x); r0.y = f2bf(v0.y); r0.z = f2bf(v0.z); r0.w = f2bf(v0.w);
        r1.x = f2bf(v1.x); r1.y = f2bf(v1.y); r1.z = f2bf(v1.z); r1.w = f2bf(v1.w);
        *(ushort4*)(X16 + i) = r0;
        *(ushort4*)(X16 + i + 4) = r1;
    } else {
        int lid = bid - 4096;
        int z = lid >> 10, r = lid & 1023;
        const float* w; u16* o;
        switch (z) {
            case 0: w = w0; o = o0; break;
            case 1: w = w1; o = o1; break;
            case 2: w = w2; o = o2; break;
            default: w = w3; o = o3; break;
        }
        int kb = (r >> 5) * 32, nb = (r & 31) * 32;
        int c = threadIdx.x & 31, r0 = threadIdx.x >> 5;
#pragma unroll
        for (int i = 0; i < 4; i++) {
            int rr = r0 + 8 * i;
            t[rr][c] = f2bf(w[(kb + rr) * D_ + nb + c]);
        }
        __syncthreads();
#pragma unroll
        for (int i = 0; i < 4; i++) {
            int rr = r0 + 8 * i;
            o[(nb + rr) * D_ + kb + c] = t[c][rr];
        }
    }
}

// ---------------------------------------------------------------------------
// R8 GEMM (best measured): C[M,N] = (A[M,K] @ BT[N,K]^T + bias) * scale.
// BM=256 x BN=128 x BK=32, 512 threads / 8 waves, tri-buffer 72KB ->
// 2 blocks/CU, counted vmcnt(3), one s_barrier per K-tile, 2-ahead prefetch.
// T1 XCD panel-affinity, T2 2-bit XOR swizzle, T5 setprio.
// ---------------------------------------------------------------------------
#define ABUF_ (256 * 32)            // u16 per A region (16KB)
#define TBUF_ ((256 + 128) * 32)    // u16 per buffer (A + B, 24KB)
#define NKT_  32                    // D_/32 K-tiles

__device__ __forceinline__ void gemm_body256(const u16* __restrict__ A,
                                             const u16* __restrict__ BT,
                                             const float* __restrict__ bias,
                                             void* __restrict__ Cout, int mode, float scale,
                                             u16* S, int nb, int mb) {
    int tid = threadIdx.x;
    int w = tid >> 6, lane = tid & 63, quad = lane >> 4, l16 = lane & 15;
    int wm = (w >> 1) * 64, wn = (w & 1) * 64;
    int x3 = l16 & 3;

    // staging source pointers (inverse-swizzled global, linear LDS dest)
    const u16* Aga[2]; const u16* Bga;
#pragma unroll
    for (int i = 0; i < 2; ++i) {
        int idx = i * 512 + tid, row = idx >> 2;
        int lu = (idx & 3) ^ (row & 3);
        Aga[i] = A + (size_t)(mb + row) * D_ + lu * 8;
    }
    {
        int row = tid >> 2;
        int lu = (tid & 3) ^ (row & 3);
        Bga = BT + (size_t)(nb + row) * D_ + lu * 8;
    }

    facc4 acc[4][4] = {};

    u16* Bu0 = S;
    u16* Bu1 = S + TBUF_;
    u16* Bu2 = S + 2 * TBUF_;

    auto stage = [&](u16* Nb, int ko) {
#pragma unroll
        for (int i = 0; i < 2; ++i) gl_lds16(Aga[i] + ko, Nb + (i * 512 + tid) * 8);
        gl_lds16(Bga + ko, Nb + ABUF_ + tid * 8);
    };
    auto compute = [&](const u16* Cb) {
        int pu = (quad ^ x3) * 8;                 // swizzled 16B-unit offset
        bfrag8 af[4], bf[4];
#pragma unroll
        for (int mt = 0; mt < 4; ++mt)
            af[mt] = *(const bfrag8*)(Cb + (wm + mt * 16 + l16) * 32 + pu);
#pragma unroll
        for (int nt = 0; nt < 4; ++nt)
            bf[nt] = *(const bfrag8*)(Cb + ABUF_ + (wn + nt * 16 + l16) * 32 + pu);
        __builtin_amdgcn_s_setprio(1);
#pragma unroll
        for (int mt = 0; mt < 4; ++mt)
#pragma unroll
            for (int nt = 0; nt < 4; ++nt)
                acc[mt][nt] = __builtin_amdgcn_mfma_f32_16x16x32_bf16(af[mt], bf[nt], acc[mt][nt], 0, 0, 0);
        __builtin_amdgcn_s_setprio(0);
    };

    // prologue: stage tiles 0,1
    stage(Bu0, 0);
    stage(Bu1, 32);

    u16 *bc = Bu0, *bn = Bu1, *bs = Bu2;
    for (int kt = 0; kt < NKT_; ++kt) {
        if (kt < NKT_ - 1) asm volatile("s_waitcnt vmcnt(3)" ::: "memory");
        else               asm volatile("s_waitcnt vmcnt(0)" ::: "memory");
        __builtin_amdgcn_sched_barrier(0);
        __builtin_amdgcn_s_barrier();
        __builtin_amdgcn_sched_barrier(0);
        if (kt + 2 < NKT_) stage(bs, (kt + 2) * 32);
        compute(bc);
        u16* tmp = bc; bc = bn; bn = bs; bs = tmp;
    }

#pragma unroll
    for (int mt = 0; mt < 4; ++mt) {
        int m_base = mb + wm + mt * 16 + quad * 4;
#pragma unroll
        for (int nt = 0; nt < 4; ++nt) {
            int n = nb + wn + nt * 16 + l16;
            float bv = bias[n];
            int h = n >> 6, dd = n & 63;
#pragma unroll
            for (int r = 0; r < 4; ++r) {
                int m = m_base + r;
                float v = (acc[mt][nt][r] + bv) * scale;
                int bi = m >> 11, s = m & (S_ - 1);
                if (mode == 0) {
                    ((u16*)Cout)[(((bi * H_ + h) * S_) + s) * DH_ + dd] = bfr(v);
                } else if (mode == 1) {
                    ((u16*)Cout)[(((bi * H_ + h) * DH_) + dd) * S_ + s] = bfr(v);
                } else {
                    ((float*)Cout)[(size_t)m * D_ + n] = v;
                }
            }
        }
    }
}

#define CE_Q 0.18033688011112042f   // log2(e)/sqrt(DH), folded into Q

// 1D grid (768): xcd = lid&7, s = lid>>3 in [0,96); z = s>>5 selects weight;
// inner = s&31: y = xcd*4 + (inner>>3) in [0,32), x = inner&7. Bijective.
__global__ __launch_bounds__(512, 4) void gemm_qkv(const u16* __restrict__ A,
                                                const u16* __restrict__ WTq, const float* __restrict__ bq, u16* __restrict__ Qb,
                                                const u16* __restrict__ WTk, const float* __restrict__ bk, u16* __restrict__ Kb,
                                                const u16* __restrict__ WTv, const float* __restrict__ bv, u16* __restrict__ VTb) {
    __shared__ __attribute__((aligned(16))) u16 Sh[3 * TBUF_];   // 72 KiB
    int lid = blockIdx.x;
    int xcd = lid & 7, s = lid >> 3;
    int z = s >> 5, inner = s & 31;
    int mb = (xcd * 4 + (inner >> 3)) * 256;
    int nb = (inner & 7) * 128;
    switch (z) {
        case 0: gemm_body256(A, WTq, bq, Qb, 0, CE_Q, Sh, nb, mb); break;   // Q pre-scaled
        case 1: gemm_body256(A, WTk, bk, Kb, 0, 1.0f, Sh, nb, mb); break;
        default: gemm_body256(A, WTv, bv, VTb, 1, 1.0f, Sh, nb, mb); break;
    }
}

__global__ __launch_bounds__(512, 4) void gemm_o(const u16* __restrict__ A,
                                              const u16* __restrict__ WTo, const float* __restrict__ bo,
                                              float* __restrict__ out) {
    __shared__ __attribute__((aligned(16))) u16 Sh[3 * TBUF_];   // 72 KiB
    int lid = blockIdx.x;
    int xcd = lid & 7, s = lid >> 3;           // s in [0,32)
    int mb = (xcd * 4 + (s >> 3)) * 256;
    int nb = (s & 7) * 128;
    gemm_body256(A, WTo, bo, out, 2, 1.0f, Sh, nb, mb);
}

// ---------------------------------------------------------------------------
// Flash attention, S^T/O^T formulation, fixed-base softmax.
// R13: V LDS 3-bit super-row swizzle. Bank math: V rows are 64B (32 keys),
// so the old per-row 2-bit swizzle gave bank-start 16*(row&1)+4*(quad^l16&3)
// -> 4 lanes per bank-group per quarter-wave = 4-way conflict (1.58x, m136).
// New: super-row sr = row>>1 (128B, 8 units); stored position p holds actual
// unit p^(sr&7); read p = ((row&1)*4+quad)^(l16>>1) -> exactly 2 lanes per
// bank-group per quarter = minimum (free). K path already optimal. Fragment
// contents bit-identical. Everything else: R10-verified structure (KVBLK=32,
// 2-buffer stage-ahead, one __syncthreads/iter, mask pack, ci remap,
// bh-affinity XCD swizzle).
// ---------------------------------------------------------------------------
// exp2 + pack + lane-transpose (bpermute) + PV accumulate for one q-tile
__device__ __forceinline__ void soft_pv(const float* p, float& lp, facc4* oaccq,
                                        const bfrag8* vf, int a0, int a1, bool qlo) {
    float rs = 0.f;
    unsigned pk[4];
#pragma unroll
    for (int j = 0; j < 4; ++j) {
        float e0 = exp2f(p[2 * j]);
        float e1 = exp2f(p[2 * j + 1]);
        rs += e0; rs += e1;
        pk[j] = __builtin_amdgcn_perm(__float_as_uint(e1), __float_as_uint(e0), 0x07060302u);
    }
    lp += rs;                                   // per-lane partial; reduced once per chunk
    union { unsigned d[4]; bfrag8 v; } pb;
    {
        unsigned lo, hi;
        lo = __builtin_amdgcn_ds_bpermute(a0, (int)pk[0]);
        hi = __builtin_amdgcn_ds_bpermute(a0, (int)pk[2]);
        pb.d[0] = qlo ? lo : hi;
        lo = __builtin_amdgcn_ds_bpermute(a0, (int)pk[1]);
        hi = __builtin_amdgcn_ds_bpermute(a0, (int)pk[3]);
        pb.d[1] = qlo ? lo : hi;
        lo = __builtin_amdgcn_ds_bpermute(a1, (int)pk[0]);
        hi = __builtin_amdgcn_ds_bpermute(a1, (int)pk[2]);
        pb.d[2] = qlo ? lo : hi;
        lo = __builtin_amdgcn_ds_bpermute(a1, (int)pk[1]);
        hi = __builtin_amdgcn_ds_bpermute(a1, (int)pk[3]);
        pb.d[3] = qlo ? lo : hi;
    }
    __builtin_amdgcn_s_setprio(1);
#pragma unroll
    for (int dt = 0; dt < 4; ++dt)
        oaccq[dt] = __builtin_amdgcn_mfma_f32_16x16x32_bf16(vf[dt], pb.v, oaccq[dt], 0, 0, 0);
    __builtin_amdgcn_s_setprio(0);
}

__global__ __launch_bounds__(256, 4) void attn(const u16* __restrict__ Q,
                                               const u16* __restrict__ K,
                                               const u16* __restrict__ VT,
                                               const int* __restrict__ pm,
                                               u16* __restrict__ Aout) {
    __shared__ __attribute__((aligned(16))) u16 Ks[2][32 * 64];   // [key][dh] 4KB x2
    __shared__ __attribute__((aligned(16))) u16 Vs[2][64 * 32];   // [sr][unit] 4KB x2
    __shared__ unsigned pms[64];                                  // packed pad mask

    int tid = threadIdx.x, w = tid >> 6, lane = tid & 63;
    int quad = lane >> 4, l16 = lane & 15;

    // lid -> (bh, ci): all 16 blocks of one bh share lid&7 (same XCD L2).
    int lid = blockIdx.x;                       // [0,1024)
    int bh  = (lid & 7) * 8 + ((lid >> 3) & 7); // [0,64)
    int g   = lid >> 6;                         // [0,16) chunk group
    int gq = g >> 2, gr = g & 3;                // balanced ci remap
    int ci = (gq == 0) ? 15 - gr : (gq == 1) ? gr : (gq == 2) ? 11 - gr : 4 + gr;
    int b = bh >> 4, h = bh & 15;

    int qbase = ci * 128;
    int qw = qbase + w * 32;                    // this wave's 32 q-rows
    int tmax = (qbase >> 5) + 3;                // tiles 0..tmax (32 keys each)

    const u16* Qp = Q + (size_t)(b * H_ + h) * S_ * DH_;
    const u16* Kp = K + (size_t)(b * H_ + h) * S_ * DH_;
    const u16* Vp = VT + (size_t)(b * H_ + h) * DH_ * S_;
    u16* Ao = Aout + (size_t)b * S_ * D_ + h * DH_;

    // build padding bitmask: wave w covers words w*16..w*16+15 (2 per ballot)
#pragma unroll
    for (int i = 0; i < 8; ++i) {
        int j2 = w * 16 + i * 2;
        u64 m = __ballot(pm[b * S_ + j2 * 32 + lane] != 0);
        if (lane == 0) { pms[j2] = (unsigned)m; pms[j2 + 1] = (unsigned)(m >> 32); }
    }

    // staging thread map (inverse-swizzled global source, linear LDS dest)
    int krow = tid >> 3, ku = tid & 7;          // K tile: 32 rows x 8x16B units
    const u16* Kg = Kp + krow * DH_ + ((ku ^ (krow & 7)) * 8);
    // V tile as 32 super-rows (2 d-rows, 8x16B units): pos p holds unit p^(sr&7)
    int vsr = tid >> 3, vpp = tid & 7;
    int vup = vpp ^ (vsr & 7);                  // actual unit to fetch
    const u16* Vg = Vp + (size_t)(vsr * 2 + (vup >> 2)) * S_ + (vup & 3) * 8;
    u16* Kl[2] = { &Ks[0][tid * 8], &Ks[1][tid * 8] };
    u16* Vl[2] = { &Vs[0][tid * 8], &Vs[1][tid * 8] };

    // swizzled read constants
    int k7 = l16 & 7;
    // V read base (loop-invariant): sr&7 == l16>>1 (dt*8 contributes 0 mod 8)
    int vbase = (l16 >> 1) * 64 + (((((l16 & 1) << 2) + quad) ^ (l16 >> 1)) * 8);

    // bpermute byte-addresses for the P^T lane permute (loop-invariant)
    int a0 = ((((2 * quad) & 3) * 16 + l16) << 2);
    int a1 = ((((2 * quad + 1) & 3) * 16 + l16) << 2);
    bool qlo = quad < 2;

    bfrag8 qf[2][2];
#pragma unroll
    for (int qt = 0; qt < 2; ++qt)
#pragma unroll
        for (int cc = 0; cc < 2; ++cc)
            qf[qt][cc] = *(const bfrag8*)(Qp + (qw + qt * 16 + l16) * DH_ + cc * 32 + quad * 8);

    facc4 oacc[2][4] = {};                      // O^T: [qt][dt], row=d, col=q=l16
    float lp[2] = {0.f, 0.f};                   // per-lane partial denominators

    // prologue: stage tile 0 into buffer 0
    gl_lds16(Kg, Kl[0]);
    gl_lds16(Vg, Vl[0]);
    __syncthreads();                            // drains vmcnt; tile 0 + pms ready
    unsigned vmn = pms[0];

    for (int t = 0; t <= tmax; ++t) {
        int cur = t & 1, nxt = cur ^ 1;
        unsigned vm = vmn;
        if (t < tmax) {                         // issue next-tile stage FIRST
            int k1 = (t + 1) * 32;
            gl_lds16(Kg + k1 * DH_, Kl[nxt]);
            gl_lds16(Vg + k1, Vl[nxt]);
            vmn = pms[t + 1];
        }
        int k0 = t * 32;
        const u16* Kc = Ks[cur];
        const u16* Vc = Vs[cur];

        // K fragments from LDS (swizzled read)
        bfrag8 kf00 = *(const bfrag8*)(Kc + (l16 * 8        + ((quad)     ^ k7)) * 8);
        bfrag8 kf01 = *(const bfrag8*)(Kc + (l16 * 8        + ((quad + 4) ^ k7)) * 8);
        bfrag8 kf10 = *(const bfrag8*)(Kc + ((l16 + 16) * 8 + ((quad)     ^ k7)) * 8);
        bfrag8 kf11 = *(const bfrag8*)(Kc + ((l16 + 16) * 8 + ((quad + 4) ^ k7)) * 8);
        bfrag8 vf[4];
#pragma unroll
        for (int dt = 0; dt < 4; ++dt)
            vf[dt] = *(const bfrag8*)(Vc + dt * 512 + vbase);

        facc4 st[2][2] = {};                    // S^T (pre-scaled): row=key, col=q
        __builtin_amdgcn_s_setprio(1);
#pragma unroll
        for (int qt = 0; qt < 2; ++qt) {
            st[qt][0] = __builtin_amdgcn_mfma_f32_16x16x32_bf16(kf00, qf[qt][0], st[qt][0], 0, 0, 0);
            st[qt][0] = __builtin_amdgcn_mfma_f32_16x16x32_bf16(kf01, qf[qt][1], st[qt][0], 0, 0, 0);
            st[qt][1] = __builtin_amdgcn_mfma_f32_16x16x32_bf16(kf10, qf[qt][0], st[qt][1], 0, 0, 0);
            st[qt][1] = __builtin_amdgcn_mfma_f32_16x16x32_bf16(kf11, qf[qt][1], st[qt][1], 0, 0, 0);
        }
        __builtin_amdgcn_s_setprio(0);

        if (vm == 0xffffffffu && k0 + 31 < qw) {
            // interior, fully valid: zero mask VALU
#pragma unroll
            for (int qt = 0; qt < 2; ++qt) {
                float p[8];
#pragma unroll
                for (int kt = 0; kt < 2; ++kt)
#pragma unroll
                    for (int r = 0; r < 4; ++r) p[kt * 4 + r] = st[qt][kt][r];
                soft_pv(p, lp[qt], oacc[qt], vf, a0, a1, qlo);
            }
        } else {
            // diagonal / padded / above-diagonal tile: per-element mask
#pragma unroll
            for (int qt = 0; qt < 2; ++qt) {
                int q0 = qw + qt * 16;
                float p[8];
#pragma unroll
                for (int kt = 0; kt < 2; ++kt)
#pragma unroll
                    for (int r = 0; r < 4; ++r) {
                        int kl = kt * 16 + quad * 4 + r;
                        bool ok = ((vm >> kl) & 1u) && (k0 + kl <= q0 + l16);
                        p[kt * 4 + r] = ok ? st[qt][kt][r] : -1e30f;
                    }
                soft_pv(p, lp[qt], oacc[qt], vf, a0, a1, qlo);
            }
        }
        __syncthreads();                        // next tile landed; cur free
    }

    // finalize: reduce l across quads, normalize, store O^T
#pragma unroll
    for (int qt = 0; qt < 2; ++qt) {
        float l = lp[qt];
        l += __shfl_xor(l, 16);
        l += __shfl_xor(l, 32);
        float linv = (l > 0.f) ? 1.f / l : 0.f;
        size_t qoff = (size_t)(qw + qt * 16 + l16) * D_;
#pragma unroll
        for (int dt = 0; dt < 4; ++dt) {
            union { u16 hh[4]; u64 q; } pk4;
#pragma unroll
            for (int r = 0; r < 4; ++r) pk4.hh[r] = bfr(oacc[qt][dt][r] * linv);
            *(u64*)(Ao + qoff + dt * 16 + quad * 4) = pk4.q;
        }
    }
}

// ---------------------------------------------------------------------------
extern "C" void kernel_launch(void* const* d_in, const int* in_sizes, int n_in,
                              void* d_out, int out_size, void* d_ws, size_t ws_size,
                              hipStream_t stream) {
    const float* x  = (const float*)d_in[0];
    const float* Wq = (const float*)d_in[1];
    const float* bq = (const float*)d_in[2];
    const float* Wk = (const float*)d_in[3];
    const float* bk = (const float*)d_in[4];
    const float* Wv = (const float*)d_in[5];
    const float* bv = (const float*)d_in[6];
    const float* Wo = (const float*)d_in[7];
    const float* bo = (const float*)d_in[8];
    const int*   pm = (const int*)d_in[9];
    float* out = (float*)d_out;

    char* ws = (char*)d_ws;
    const size_t SZ_XD = (size_t)M_ * D_ * 2;   // 16 MiB bf16 [M,D]
    const size_t SZ_W  = (size_t)D_ * D_ * 2;   //  2 MiB bf16 [D,D]
    u16* X16 = (u16*)ws;                 // reused as attended output (safe: X16's
                                         // last read is the V GEMM; attn writes later)
    u16* WTq = (u16*)(ws + SZ_XD);
    u16* WTk = (u16*)(ws + SZ_XD + SZ_W);
    u16* WTv = (u16*)(ws + SZ_XD + 2 * SZ_W);
    u16* WTo = (u16*)(ws + SZ_XD + 3 * SZ_W);
    u16* Qb  = (u16*)(ws + SZ_XD + 4 * SZ_W);
    u16* Kb  = (u16*)(ws + 2 * SZ_XD + 4 * SZ_W);
    u16* VTb = (u16*)(ws + 3 * SZ_XD + 4 * SZ_W);
    u16* Att = X16;

    prep<<<dim3(8192), 256, 0, stream>>>(x, X16, Wq, Wk, Wv, Wo, WTq, WTk, WTv, WTo);

    gemm_qkv<<<dim3(768), 512, 0, stream>>>(X16, WTq, bq, Qb, WTk, bk, Kb, WTv, bv, VTb);

    attn<<<dim3(1024), 256, 0, stream>>>(Qb, Kb, VTb, pm, Att);

    gemm_o<<<dim3(256), 512, 0, stream>>>(Att, WTo, bo, out);
}

// Round 15
// 249.819 us; speedup vs baseline: 1.1737x; 1.0250x over previous
//
#include <hip/hip_runtime.h>
#include <hip/hip_bf16.h>

#define B_   4
#define S_   2048
#define D_   1024
#define H_   16
#define DH_  64
#define M_   (B_ * S_)

typedef __attribute__((ext_vector_type(8))) short  bfrag8;   // 8 bf16 = 4 VGPRs
typedef __attribute__((ext_vector_type(4))) float  facc4;    // 4 fp32 accum
typedef unsigned short u16;
typedef unsigned long long u64;

__device__ __forceinline__ u16 f2bf(float f) {
    union { __hip_bfloat16 h; u16 u; } c;
    c.h = __float2bfloat16(f);
    return c.u;
}

// manual RNE fp32->bf16 (finite inputs only)
__device__ __forceinline__ u16 bfr(float f) {
    unsigned b = __float_as_uint(f);
    return (u16)((b + 0x7FFFu + ((b >> 16) & 1u)) >> 16);
}

// async global->LDS, 16B per lane; LDS dest must be wave-uniform base + lane*16
__device__ __forceinline__ void gl_lds16(const u16* g, u16* l) {
    __builtin_amdgcn_global_load_lds((const __attribute__((address_space(1))) void*)g,
                                     (__attribute__((address_space(3))) void*)l,
                                     16, 0, 0);
}

// ---------------------------------------------------------------------------
// prep: fused input conversion.
// bid < 4096:  fp32 x -> bf16 X16, 8 elems/thread (float4 x2 / ushort4 x2).
// bid >= 4096: fp32 W[k][n] -> bf16 WT[n][k], 32x32 LDS transpose tiles.
// R14: W-phase vectorized to 16B/lane both sides (G13): load float4
// (thread = row,col4), store ushort4 gathered from the padded LDS tile.
// ---------------------------------------------------------------------------
__global__ __launch_bounds__(256) void prep(const float* __restrict__ x, u16* __restrict__ X16,
                                            const float* __restrict__ w0, const float* __restrict__ w1,
                                            const float* __restrict__ w2, const float* __restrict__ w3,
                                            u16* __restrict__ o0, u16* __restrict__ o1,
                                            u16* __restrict__ o2, u16* __restrict__ o3) {
    __shared__ u16 t[32][33];
    int bid = blockIdx.x;
    if (bid < 4096) {
        int i = (bid * 256 + threadIdx.x) * 8;
        float4 v0 = *(const float4*)(x + i);
        float4 v1 = *(const float4*)(x + i + 4);
        ushort4 r0, r1;
        r0.x = f2bf(v0.x); r0.y = f2bf(v0.y); r0.z = f2bf(v0.z); r0.w = f2bf(v0.w);
        r1.x = f2bf(v1.x); r1.y = f2bf(v1.y); r1.z = f2bf(v1.z); r1.w = f2bf(v1.w);
        *(ushort4*)(X16 + i) = r0;
        *(ushort4*)(X16 + i + 4) = r1;
    } else {
        int lid = bid - 4096;
        int z = lid >> 10, r = lid & 1023;
        const float* w; u16* o;
        switch (z) {
            case 0: w = w0; o = o0; break;
            case 1: w = w1; o = o1; break;
            case 2: w = w2; o = o2; break;
            default: w = w3; o = o3; break;
        }
        int kb = (r >> 5) * 32, nb = (r & 31) * 32;
        int row = threadIdx.x >> 3, col4 = (threadIdx.x & 7) * 4;
        // load: one float4 per thread (16B/lane, coalesced 8 lanes/row)
        float4 v = *(const float4*)(w + (kb + row) * D_ + nb + col4);
        t[row][col4]     = f2bf(v.x);
        t[row][col4 + 1] = f2bf(v.y);
        t[row][col4 + 2] = f2bf(v.z);
        t[row][col4 + 3] = f2bf(v.w);
        __syncthreads();
        // store: one ushort4 per thread of the TRANSPOSED tile (8B/lane)
        ushort4 s;
        s.x = t[col4][row]; s.y = t[col4 + 1][row];
        s.z = t[col4 + 2][row]; s.w = t[col4 + 3][row];
        *(ushort4*)(o + (nb + row) * D_ + kb + col4) = s;
    }
}

// ---------------------------------------------------------------------------
// R8 GEMM (best measured): C[M,N] = (A[M,K] @ BT[N,K]^T + bias) * scale.
// BM=256 x BN=128 x BK=32, 512 threads / 8 waves, tri-buffer 72KB ->
// 2 blocks/CU, counted vmcnt(3), one s_barrier per K-tile, 2-ahead prefetch.
// T1 XCD panel-affinity, T2 2-bit XOR swizzle, T5 setprio.
// ---------------------------------------------------------------------------
#define ABUF_ (256 * 32)            // u16 per A region (16KB)
#define TBUF_ ((256 + 128) * 32)    // u16 per buffer (A + B, 24KB)
#define NKT_  32                    // D_/32 K-tiles

__device__ __forceinline__ void gemm_body256(const u16* __restrict__ A,
                                             const u16* __restrict__ BT,
                                             const float* __restrict__ bias,
                                             void* __restrict__ Cout, int mode, float scale,
                                             u16* S, int nb, int mb) {
    int tid = threadIdx.x;
    int w = tid >> 6, lane = tid & 63, quad = lane >> 4, l16 = lane & 15;
    int wm = (w >> 1) * 64, wn = (w & 1) * 64;
    int x3 = l16 & 3;

    // staging source pointers (inverse-swizzled global, linear LDS dest)
    const u16* Aga[2]; const u16* Bga;
#pragma unroll
    for (int i = 0; i < 2; ++i) {
        int idx = i * 512 + tid, row = idx >> 2;
        int lu = (idx & 3) ^ (row & 3);
        Aga[i] = A + (size_t)(mb + row) * D_ + lu * 8;
    }
    {
        int row = tid >> 2;
        int lu = (tid & 3) ^ (row & 3);
        Bga = BT + (size_t)(nb + row) * D_ + lu * 8;
    }

    facc4 acc[4][4] = {};

    u16* Bu0 = S;
    u16* Bu1 = S + TBUF_;
    u16* Bu2 = S + 2 * TBUF_;

    auto stage = [&](u16* Nb, int ko) {
#pragma unroll
        for (int i = 0; i < 2; ++i) gl_lds16(Aga[i] + ko, Nb + (i * 512 + tid) * 8);
        gl_lds16(Bga + ko, Nb + ABUF_ + tid * 8);
    };
    auto compute = [&](const u16* Cb) {
        int pu = (quad ^ x3) * 8;                 // swizzled 16B-unit offset
        bfrag8 af[4], bf[4];
#pragma unroll
        for (int mt = 0; mt < 4; ++mt)
            af[mt] = *(const bfrag8*)(Cb + (wm + mt * 16 + l16) * 32 + pu);
#pragma unroll
        for (int nt = 0; nt < 4; ++nt)
            bf[nt] = *(const bfrag8*)(Cb + ABUF_ + (wn + nt * 16 + l16) * 32 + pu);
        __builtin_amdgcn_s_setprio(1);
#pragma unroll
        for (int mt = 0; mt < 4; ++mt)
#pragma unroll
            for (int nt = 0; nt < 4; ++nt)
                acc[mt][nt] = __builtin_amdgcn_mfma_f32_16x16x32_bf16(af[mt], bf[nt], acc[mt][nt], 0, 0, 0);
        __builtin_amdgcn_s_setprio(0);
    };

    // prologue: stage tiles 0,1
    stage(Bu0, 0);
    stage(Bu1, 32);

    u16 *bc = Bu0, *bn = Bu1, *bs = Bu2;
    for (int kt = 0; kt < NKT_; ++kt) {
        if (kt < NKT_ - 1) asm volatile("s_waitcnt vmcnt(3)" ::: "memory");
        else               asm volatile("s_waitcnt vmcnt(0)" ::: "memory");
        __builtin_amdgcn_sched_barrier(0);
        __builtin_amdgcn_s_barrier();
        __builtin_amdgcn_sched_barrier(0);
        if (kt + 2 < NKT_) stage(bs, (kt + 2) * 32);
        compute(bc);
        u16* tmp = bc; bc = bn; bn = bs; bs = tmp;
    }

#pragma unroll
    for (int mt = 0; mt < 4; ++mt) {
        int m_base = mb + wm + mt * 16 + quad * 4;
#pragma unroll
        for (int nt = 0; nt < 4; ++nt) {
            int n = nb + wn + nt * 16 + l16;
            float bv = bias[n];
            int h = n >> 6, dd = n & 63;
#pragma unroll
            for (int r = 0; r < 4; ++r) {
                int m = m_base + r;
                float v = (acc[mt][nt][r] + bv) * scale;
                int bi = m >> 11, s = m & (S_ - 1);
                if (mode == 0) {
                    ((u16*)Cout)[(((bi * H_ + h) * S_) + s) * DH_ + dd] = bfr(v);
                } else if (mode == 1) {
                    ((u16*)Cout)[(((bi * H_ + h) * DH_) + dd) * S_ + s] = bfr(v);
                } else {
                    ((float*)Cout)[(size_t)m * D_ + n] = v;
                }
            }
        }
    }
}

#define CE_Q 0.18033688011112042f   // log2(e)/sqrt(DH), folded into Q

// 1D grid (768): xcd = lid&7, s = lid>>3 in [0,96); z = s>>5 selects weight;
// inner = s&31: y = xcd*4 + (inner>>3) in [0,32), x = inner&7. Bijective.
__global__ __launch_bounds__(512, 4) void gemm_qkv(const u16* __restrict__ A,
                                                const u16* __restrict__ WTq, const float* __restrict__ bq, u16* __restrict__ Qb,
                                                const u16* __restrict__ WTk, const float* __restrict__ bk, u16* __restrict__ Kb,
                                                const u16* __restrict__ WTv, const float* __restrict__ bv, u16* __restrict__ VTb) {
    __shared__ __attribute__((aligned(16))) u16 Sh[3 * TBUF_];   // 72 KiB
    int lid = blockIdx.x;
    int xcd = lid & 7, s = lid >> 3;
    int z = s >> 5, inner = s & 31;
    int mb = (xcd * 4 + (inner >> 3)) * 256;
    int nb = (inner & 7) * 128;
    switch (z) {
        case 0: gemm_body256(A, WTq, bq, Qb, 0, CE_Q, Sh, nb, mb); break;   // Q pre-scaled
        case 1: gemm_body256(A, WTk, bk, Kb, 0, 1.0f, Sh, nb, mb); break;
        default: gemm_body256(A, WTv, bv, VTb, 1, 1.0f, Sh, nb, mb); break;
    }
}

__global__ __launch_bounds__(512, 4) void gemm_o(const u16* __restrict__ A,
                                              const u16* __restrict__ WTo, const float* __restrict__ bo,
                                              float* __restrict__ out) {
    __shared__ __attribute__((aligned(16))) u16 Sh[3 * TBUF_];   // 72 KiB
    int lid = blockIdx.x;
    int xcd = lid & 7, s = lid >> 3;           // s in [0,32)
    int mb = (xcd * 4 + (s >> 3)) * 256;
    int nb = (s & 7) * 128;
    gemm_body256(A, WTo, bo, out, 2, 1.0f, Sh, nb, mb);
}

// ---------------------------------------------------------------------------
// Flash attention, S^T/O^T formulation, fixed-base softmax (best measured).
// KVBLK=32, 2-buffer stage-ahead, ONE __syncthreads/iter, in-kernel mask
// pack, balanced ci remap, bh-affinity XCD swizzle. R13 V super-row 3-bit
// swizzle kept (bank conflicts 6.68M -> 4.46M; time-neutral but free).
// ---------------------------------------------------------------------------
// exp2 + pack + lane-transpose (bpermute) + PV accumulate for one q-tile
__device__ __forceinline__ void soft_pv(const float* p, float& lp, facc4* oaccq,
                                        const bfrag8* vf, int a0, int a1, bool qlo) {
    float rs = 0.f;
    unsigned pk[4];
#pragma unroll
    for (int j = 0; j < 4; ++j) {
        float e0 = exp2f(p[2 * j]);
        float e1 = exp2f(p[2 * j + 1]);
        rs += e0; rs += e1;
        pk[j] = __builtin_amdgcn_perm(__float_as_uint(e1), __float_as_uint(e0), 0x07060302u);
    }
    lp += rs;                                   // per-lane partial; reduced once per chunk
    union { unsigned d[4]; bfrag8 v; } pb;
    {
        unsigned lo, hi;
        lo = __builtin_amdgcn_ds_bpermute(a0, (int)pk[0]);
        hi = __builtin_amdgcn_ds_bpermute(a0, (int)pk[2]);
        pb.d[0] = qlo ? lo : hi;
        lo = __builtin_amdgcn_ds_bpermute(a0, (int)pk[1]);
        hi = __builtin_amdgcn_ds_bpermute(a0, (int)pk[3]);
        pb.d[1] = qlo ? lo : hi;
        lo = __builtin_amdgcn_ds_bpermute(a1, (int)pk[0]);
        hi = __builtin_amdgcn_ds_bpermute(a1, (int)pk[2]);
        pb.d[2] = qlo ? lo : hi;
        lo = __builtin_amdgcn_ds_bpermute(a1, (int)pk[1]);
        hi = __builtin_amdgcn_ds_bpermute(a1, (int)pk[3]);
        pb.d[3] = qlo ? lo : hi;
    }
    __builtin_amdgcn_s_setprio(1);
#pragma unroll
    for (int dt = 0; dt < 4; ++dt)
        oaccq[dt] = __builtin_amdgcn_mfma_f32_16x16x32_bf16(vf[dt], pb.v, oaccq[dt], 0, 0, 0);
    __builtin_amdgcn_s_setprio(0);
}

__global__ __launch_bounds__(256, 4) void attn(const u16* __restrict__ Q,
                                               const u16* __restrict__ K,
                                               const u16* __restrict__ VT,
                                               const int* __restrict__ pm,
                                               u16* __restrict__ Aout) {
    __shared__ __attribute__((aligned(16))) u16 Ks[2][32 * 64];   // [key][dh] 4KB x2
    __shared__ __attribute__((aligned(16))) u16 Vs[2][64 * 32];   // [sr][unit] 4KB x2
    __shared__ unsigned pms[64];                                  // packed pad mask

    int tid = threadIdx.x, w = tid >> 6, lane = tid & 63;
    int quad = lane >> 4, l16 = lane & 15;

    // lid -> (bh, ci): all 16 blocks of one bh share lid&7 (same XCD L2).
    int lid = blockIdx.x;                       // [0,1024)
    int bh  = (lid & 7) * 8 + ((lid >> 3) & 7); // [0,64)
    int g   = lid >> 6;                         // [0,16) chunk group
    int gq = g >> 2, gr = g & 3;                // balanced ci remap
    int ci = (gq == 0) ? 15 - gr : (gq == 1) ? gr : (gq == 2) ? 11 - gr : 4 + gr;
    int b = bh >> 4, h = bh & 15;

    int qbase = ci * 128;
    int qw = qbase + w * 32;                    // this wave's 32 q-rows
    int tmax = (qbase >> 5) + 3;                // tiles 0..tmax (32 keys each)

    const u16* Qp = Q + (size_t)(b * H_ + h) * S_ * DH_;
    const u16* Kp = K + (size_t)(b * H_ + h) * S_ * DH_;
    const u16* Vp = VT + (size_t)(b * H_ + h) * DH_ * S_;
    u16* Ao = Aout + (size_t)b * S_ * D_ + h * DH_;

    // build padding bitmask: wave w covers words w*16..w*16+15 (2 per ballot)
#pragma unroll
    for (int i = 0; i < 8; ++i) {
        int j2 = w * 16 + i * 2;
        u64 m = __ballot(pm[b * S_ + j2 * 32 + lane] != 0);
        if (lane == 0) { pms[j2] = (unsigned)m; pms[j2 + 1] = (unsigned)(m >> 32); }
    }

    // staging thread map (inverse-swizzled global source, linear LDS dest)
    int krow = tid >> 3, ku = tid & 7;          // K tile: 32 rows x 8x16B units
    const u16* Kg = Kp + krow * DH_ + ((ku ^ (krow & 7)) * 8);
    // V tile as 32 super-rows (2 d-rows, 8x16B units): pos p holds unit p^(sr&7)
    int vsr = tid >> 3, vpp = tid & 7;
    int vup = vpp ^ (vsr & 7);                  // actual unit to fetch
    const u16* Vg = Vp + (size_t)(vsr * 2 + (vup >> 2)) * S_ + (vup & 3) * 8;
    u16* Kl[2] = { &Ks[0][tid * 8], &Ks[1][tid * 8] };
    u16* Vl[2] = { &Vs[0][tid * 8], &Vs[1][tid * 8] };

    // swizzled read constants
    int k7 = l16 & 7;
    // V read base (loop-invariant): sr&7 == l16>>1 (dt*8 contributes 0 mod 8)
    int vbase = (l16 >> 1) * 64 + (((((l16 & 1) << 2) + quad) ^ (l16 >> 1)) * 8);

    // bpermute byte-addresses for the P^T lane permute (loop-invariant)
    int a0 = ((((2 * quad) & 3) * 16 + l16) << 2);
    int a1 = ((((2 * quad + 1) & 3) * 16 + l16) << 2);
    bool qlo = quad < 2;

    bfrag8 qf[2][2];
#pragma unroll
    for (int qt = 0; qt < 2; ++qt)
#pragma unroll
        for (int cc = 0; cc < 2; ++cc)
            qf[qt][cc] = *(const bfrag8*)(Qp + (qw + qt * 16 + l16) * DH_ + cc * 32 + quad * 8);

    facc4 oacc[2][4] = {};                      // O^T: [qt][dt], row=d, col=q=l16
    float lp[2] = {0.f, 0.f};                   // per-lane partial denominators

    // prologue: stage tile 0 into buffer 0
    gl_lds16(Kg, Kl[0]);
    gl_lds16(Vg, Vl[0]);
    __syncthreads();                            // drains vmcnt; tile 0 + pms ready
    unsigned vmn = pms[0];

    for (int t = 0; t <= tmax; ++t) {
        int cur = t & 1, nxt = cur ^ 1;
        unsigned vm = vmn;
        if (t < tmax) {                         // issue next-tile stage FIRST
            int k1 = (t + 1) * 32;
            gl_lds16(Kg + k1 * DH_, Kl[nxt]);
            gl_lds16(Vg + k1, Vl[nxt]);
            vmn = pms[t + 1];
        }
        int k0 = t * 32;
        const u16* Kc = Ks[cur];
        const u16* Vc = Vs[cur];

        // K fragments from LDS (swizzled read)
        bfrag8 kf00 = *(const bfrag8*)(Kc + (l16 * 8        + ((quad)     ^ k7)) * 8);
        bfrag8 kf01 = *(const bfrag8*)(Kc + (l16 * 8        + ((quad + 4) ^ k7)) * 8);
        bfrag8 kf10 = *(const bfrag8*)(Kc + ((l16 + 16) * 8 + ((quad)     ^ k7)) * 8);
        bfrag8 kf11 = *(const bfrag8*)(Kc + ((l16 + 16) * 8 + ((quad + 4) ^ k7)) * 8);
        bfrag8 vf[4];
#pragma unroll
        for (int dt = 0; dt < 4; ++dt)
            vf[dt] = *(const bfrag8*)(Vc + dt * 512 + vbase);

        facc4 st[2][2] = {};                    // S^T (pre-scaled): row=key, col=q
        __builtin_amdgcn_s_setprio(1);
#pragma unroll
        for (int qt = 0; qt < 2; ++qt) {
            st[qt][0] = __builtin_amdgcn_mfma_f32_16x16x32_bf16(kf00, qf[qt][0], st[qt][0], 0, 0, 0);
            st[qt][0] = __builtin_amdgcn_mfma_f32_16x16x32_bf16(kf01, qf[qt][1], st[qt][0], 0, 0, 0);
            st[qt][1] = __builtin_amdgcn_mfma_f32_16x16x32_bf16(kf10, qf[qt][0], st[qt][1], 0, 0, 0);
            st[qt][1] = __builtin_amdgcn_mfma_f32_16x16x32_bf16(kf11, qf[qt][1], st[qt][1], 0, 0, 0);
        }
        __builtin_amdgcn_s_setprio(0);

        if (vm == 0xffffffffu && k0 + 31 < qw) {
            // interior, fully valid: zero mask VALU
#pragma unroll
            for (int qt = 0; qt < 2; ++qt) {
                float p[8];
#pragma unroll
                for (int kt = 0; kt < 2; ++kt)
#pragma unroll
                    for (int r = 0; r < 4; ++r) p[kt * 4 + r] = st[qt][kt][r];
                soft_pv(p, lp[qt], oacc[qt], vf, a0, a1, qlo);
            }
        } else {
            // diagonal / padded / above-diagonal tile: per-element mask
#pragma unroll
            for (int qt = 0; qt < 2; ++qt) {
                int q0 = qw + qt * 16;
                float p[8];
#pragma unroll
                for (int kt = 0; kt < 2; ++kt)
#pragma unroll
                    for (int r = 0; r < 4; ++r) {
                        int kl = kt * 16 + quad * 4 + r;
                        bool ok = ((vm >> kl) & 1u) && (k0 + kl <= q0 + l16);
                        p[kt * 4 + r] = ok ? st[qt][kt][r] : -1e30f;
                    }
                soft_pv(p, lp[qt], oacc[qt], vf, a0, a1, qlo);
            }
        }
        __syncthreads();                        // next tile landed; cur free
    }

    // finalize: reduce l across quads, normalize, store O^T
#pragma unroll
    for (int qt = 0; qt < 2; ++qt) {
        float l = lp[qt];
        l += __shfl_xor(l, 16);
        l += __shfl_xor(l, 32);
        float linv = (l > 0.f) ? 1.f / l : 0.f;
        size_t qoff = (size_t)(qw + qt * 16 + l16) * D_;
#pragma unroll
        for (int dt = 0; dt < 4; ++dt) {
            union { u16 hh[4]; u64 q; } pk4;
#pragma unroll
            for (int r = 0; r < 4; ++r) pk4.hh[r] = bfr(oacc[qt][dt][r] * linv);
            *(u64*)(Ao + qoff + dt * 16 + quad * 4) = pk4.q;
        }
    }
}

// ---------------------------------------------------------------------------
extern "C" void kernel_launch(void* const* d_in, const int* in_sizes, int n_in,
                              void* d_out, int out_size, void* d_ws, size_t ws_size,
                              hipStream_t stream) {
    const float* x  = (const float*)d_in[0];
    const float* Wq = (const float*)d_in[1];
    const float* bq = (const float*)d_in[2];
    const float* Wk = (const float*)d_in[3];
    const float* bk = (const float*)d_in[4];
    const float* Wv = (const float*)d_in[5];
    const float* bv = (const float*)d_in[6];
    const float* Wo = (const float*)d_in[7];
    const float* bo = (const float*)d_in[8];
    const int*   pm = (const int*)d_in[9];
    float* out = (float*)d_out;

    char* ws = (char*)d_ws;
    const size_t SZ_XD = (size_t)M_ * D_ * 2;   // 16 MiB bf16 [M,D]
    const size_t SZ_W  = (size_t)D_ * D_ * 2;   //  2 MiB bf16 [D,D]
    u16* X16 = (u16*)ws;                 // reused as attended output (safe: X16's
                                         // last read is the V GEMM; attn writes later)
    u16* WTq = (u16*)(ws + SZ_XD);
    u16* WTk = (u16*)(ws + SZ_XD + SZ_W);
    u16* WTv = (u16*)(ws + SZ_XD + 2 * SZ_W);
    u16* WTo = (u16*)(ws + SZ_XD + 3 * SZ_W);
    u16* Qb  = (u16*)(ws + SZ_XD + 4 * SZ_W);
    u16* Kb  = (u16*)(ws + 2 * SZ_XD + 4 * SZ_W);
    u16* VTb = (u16*)(ws + 3 * SZ_XD + 4 * SZ_W);
    u16* Att = X16;

    prep<<<dim3(8192), 256, 0, stream>>>(x, X16, Wq, Wk, Wv, Wo, WTq, WTk, WTv, WTo);

    gemm_qkv<<<dim3(768), 512, 0, stream>>>(X16, WTq, bq, Qb, WTk, bk, Kb, WTv, bv, VTb);

    attn<<<dim3(1024), 256, 0, stream>>>(Qb, Kb, VTb, pm, Att);

    gemm_o<<<dim3(256), 512, 0, stream>>>(Att, WTo, bo, out);
}